// Round 10
// baseline (268.262 us; speedup 1.0000x reference)
//
#include <hip/hip_runtime.h>
#include <hip/hip_fp16.h>

#define DIN 128
#define DH 64
#define NBINS 512      // bin = dst >> 7 ; n=50000 -> bins 0..390 used
#define BIN_SHIFT 7
#define BIN_NODES 128
#define ETILE 4096     // edges per histogram/scatter block
#define EBUF 4096      // LDS edge buffer per bin (avg fill ~2046)
#define HROWS 32       // rows per head block (64 threads, 2 lanes/row)

__device__ inline unsigned pack_half2(float a, float b) {
  __half2 h = __floats2half2_rn(a, b);
  return *(unsigned*)&h;
}
__device__ inline float2 unpack_half2(unsigned u) {
  __half2 h = *(__half2*)&u;
  return __half22float2(h);
}

// ---------------- zero helper (capture-safe) ----------------
__global__ __launch_bounds__(512) void k_zero(int* __restrict__ p, int n) {
  int i = blockIdx.x * blockDim.x + threadIdx.x;
  if (i < n) p[i] = 0;
}

// ---------------- A: fused  gemm1 (x@W1 -> fp16 g1)  ||  bin histogram ------
__global__ __launch_bounds__(256) void k_fusedA(const float* __restrict__ x,
                                                const float* __restrict__ W1,
                                                __half* __restrict__ g1,
                                                const int* __restrict__ dst,
                                                int* __restrict__ binTot,
                                                int n, int e, int gG) {
  __shared__ float xsT[32][132];
  __shared__ float ws[32 * 64];
  __shared__ int hh[NBINS];
  int t = threadIdx.x;
  int bid = blockIdx.x;

  if (bid >= gG) {  // ---- histogram part ----
    int b = bid - gG;
    for (int i = t; i < NBINS; i += 256) hh[i] = 0;
    __syncthreads();
    int lo = b * ETILE, hi = lo + ETILE; if (hi > e) hi = e;
    for (int i = lo + t; i < hi; i += 256) atomicAdd(&hh[dst[i] >> BIN_SHIFT], 1);
    __syncthreads();
    for (int i = t; i < NBINS; i += 256) if (hh[i]) atomicAdd(&binTot[i], hh[i]);
    return;
  }

  // ---- gemm part: [n,128]@[128,64] -> fp16 ----
  int row0 = bid * 128;
  int rg = t >> 4, cg = t & 15;
  int r0 = rg * 8, c0 = cg * 4;
  int lr = t >> 3, kq = t & 7;
  float4 acc[8];
#pragma unroll
  for (int i = 0; i < 8; ++i) acc[i] = make_float4(0.f, 0.f, 0.f, 0.f);

  for (int kc = 0; kc < DIN; kc += 32) {
#pragma unroll
    for (int it = 0; it < 4; ++it) {
      int r = it * 32 + lr;
      int gr = row0 + r;
      float4 v = make_float4(0.f, 0.f, 0.f, 0.f);
      if (gr < n) v = *(const float4*)&x[(size_t)gr * DIN + kc + kq * 4];
      xsT[kq * 4 + 0][r] = v.x;
      xsT[kq * 4 + 1][r] = v.y;
      xsT[kq * 4 + 2][r] = v.z;
      xsT[kq * 4 + 3][r] = v.w;
    }
#pragma unroll
    for (int j = 0; j < 8; ++j) ws[t + j * 256] = W1[(size_t)kc * 64 + t + j * 256];
    __syncthreads();
#pragma unroll
    for (int k = 0; k < 32; ++k) {
      float4 xa = *(const float4*)&xsT[k][r0];
      float4 xb = *(const float4*)&xsT[k][r0 + 4];
      float4 wv = *(const float4*)&ws[k * 64 + c0];
      float xr[8] = {xa.x, xa.y, xa.z, xa.w, xb.x, xb.y, xb.z, xb.w};
#pragma unroll
      for (int i = 0; i < 8; ++i) {
        acc[i].x = fmaf(xr[i], wv.x, acc[i].x);
        acc[i].y = fmaf(xr[i], wv.y, acc[i].y);
        acc[i].z = fmaf(xr[i], wv.z, acc[i].z);
        acc[i].w = fmaf(xr[i], wv.w, acc[i].w);
      }
    }
    __syncthreads();
  }
#pragma unroll
  for (int i = 0; i < 8; ++i) {
    int gr = row0 + r0 + i;
    if (gr < n) {
      uint2 u;
      u.x = pack_half2(acc[i].x, acc[i].y);
      u.y = pack_half2(acc[i].z, acc[i].w);
      *(uint2*)&g1[(size_t)gr * 64 + c0] = u;
    }
  }
}

// ---------------- B: scan 512 bin totals -> binOff, init binCur --------------
__global__ __launch_bounds__(512) void k_binscan(const int* __restrict__ binTot,
                                                 int* __restrict__ binOff,
                                                 int* __restrict__ binCur, int e) {
  __shared__ int sm[NBINS];
  int t = threadIdx.x;
  int v = binTot[t];
  sm[t] = v;
  __syncthreads();
  for (int ofs = 1; ofs < NBINS; ofs <<= 1) {
    int u = (t >= ofs) ? sm[t - ofs] : 0;
    __syncthreads();
    sm[t] += u;
    __syncthreads();
  }
  int ex = sm[t] - v;  // exclusive
  binOff[t] = ex;
  binCur[t] = ex;
  if (t == NBINS - 1) binOff[NBINS] = sm[NBINS - 1];
}

// ---------------- C: scatter into bin-grouped order (atomic cursors) ---------
__global__ __launch_bounds__(256) void k_scatter2(const int* __restrict__ src,
                                                  const int* __restrict__ dst,
                                                  int* __restrict__ binCur,
                                                  int* __restrict__ sp, int e) {
  __shared__ int hh[NBINS];
  __shared__ int base[NBINS];
  int t = threadIdx.x;
  for (int i = t; i < NBINS; i += 256) hh[i] = 0;
  __syncthreads();
  int lo = blockIdx.x * ETILE, hi = lo + ETILE; if (hi > e) hi = e;
  for (int i = lo + t; i < hi; i += 256) atomicAdd(&hh[dst[i] >> BIN_SHIFT], 1);
  __syncthreads();
  for (int i = t; i < NBINS; i += 256) {
    int c = hh[i];
    base[i] = c ? atomicAdd(&binCur[i], c) : 0;
  }
  __syncthreads();
  for (int i = t; i < NBINS; i += 256) hh[i] = 0;  // reuse as local cursors
  __syncthreads();
  for (int i = lo + t; i < hi; i += 256) {
    int d = dst[i];
    int bn = d >> BIN_SHIFT;
    int pos = base[bn] + atomicAdd(&hh[bn], 1);
    sp[pos] = (src[i] << BIN_SHIFT) | (d & (BIN_NODES - 1));
  }
}

// ---------------- D: per-bin deg + local scan -> off/dinv/srcs --------------
__global__ __launch_bounds__(256) void k_bincsr(const int* __restrict__ sp,
                                                const int* __restrict__ binOff,
                                                int* __restrict__ off,
                                                float* __restrict__ dinv,
                                                int* __restrict__ srcs,
                                                int n, int e) {
  __shared__ int dl[BIN_NODES];
  __shared__ int sc[BIN_NODES];
  __shared__ int curl[BIN_NODES];
  __shared__ int ebuf[EBUF];
  int b = blockIdx.x, t = threadIdx.x;
  if (t < BIN_NODES) dl[t] = 0;
  __syncthreads();
  int e0 = binOff[b];
  int e1 = binOff[b + 1];
  for (int i = e0 + t; i < e1; i += 256) {
    int u = sp[i];
    int k = i - e0;
    if (k < EBUF) ebuf[k] = u;
    atomicAdd(&dl[u & (BIN_NODES - 1)], 1);
  }
  __syncthreads();
  if (t < BIN_NODES) sc[t] = dl[t];
  __syncthreads();
  for (int ofs = 1; ofs < BIN_NODES; ofs <<= 1) {
    int v = (t < BIN_NODES && t >= ofs) ? sc[t - ofs] : 0;
    __syncthreads();
    if (t < BIN_NODES) sc[t] += v;
    __syncthreads();
  }
  int nbase = b * BIN_NODES;
  if (t < BIN_NODES) {
    int ex = e0 + sc[t] - dl[t];
    curl[t] = ex;
    int node = nbase + t;
    if (node < n) {
      off[node] = ex;
      dinv[node] = rsqrtf((float)(dl[t] + 1));
    }
  }
  if (b == 0 && t == 0) off[n] = e;
  __syncthreads();
  for (int i = e0 + t; i < e1; i += 256) {
    int k = i - e0;
    int u = (k < EBUF) ? ebuf[k] : sp[i];
    int l = u & (BIN_NODES - 1);
    int pos = atomicAdd(&curl[l], 1);
    srcs[pos] = u >> BIN_SHIFT;
  }
}

// ---------------- E/F: CSR gather-aggregate (fp16 in, fp16 out) -------------
__global__ __launch_bounds__(256) void k_agg(const __half* __restrict__ gh,
                                             const int* __restrict__ off,
                                             const int* __restrict__ srcs,
                                             const float* __restrict__ dinv,
                                             const float* __restrict__ bias,
                                             __half* __restrict__ out, int n, int relu) {
  int gid = blockIdx.x * 4 + (threadIdx.x >> 6);
  if (gid >= n) return;
  gid = __builtin_amdgcn_readfirstlane(gid);
  int lane = threadIdx.x & 63;
  int grp = lane >> 4;         // 0..3: edge slot
  int d4 = (lane & 15) * 4;    // feature quad
  float di = dinv[gid];
  float4 acc = make_float4(0.f, 0.f, 0.f, 0.f);
  if (grp == 0) {  // self-loop counted once
    uint2 raw = *(const uint2*)(gh + (size_t)gid * DH + d4);
    float2 f0 = unpack_half2(raw.x), f1 = unpack_half2(raw.y);
    float s = di * di;
    acc.x = f0.x * s; acc.y = f0.y * s; acc.z = f1.x * s; acc.w = f1.y * s;
  }
  int b0 = off[gid], b1 = off[gid + 1];
  int j = b0 + grp;
  for (; j + 12 < b1; j += 16) {  // 4 rows in flight per group
    int s0 = srcs[j], s1 = srcs[j + 4], s2 = srcs[j + 8], s3 = srcs[j + 12];
    float w0 = dinv[s0] * di, w1 = dinv[s1] * di;
    float w2 = dinv[s2] * di, w3 = dinv[s3] * di;
    uint2 r0 = *(const uint2*)(gh + (size_t)s0 * DH + d4);
    uint2 r1 = *(const uint2*)(gh + (size_t)s1 * DH + d4);
    uint2 r2 = *(const uint2*)(gh + (size_t)s2 * DH + d4);
    uint2 r3 = *(const uint2*)(gh + (size_t)s3 * DH + d4);
    float2 a0 = unpack_half2(r0.x), a1 = unpack_half2(r0.y);
    float2 c0 = unpack_half2(r1.x), c1 = unpack_half2(r1.y);
    float2 e0 = unpack_half2(r2.x), e1 = unpack_half2(r2.y);
    float2 g0 = unpack_half2(r3.x), g1 = unpack_half2(r3.y);
    acc.x = fmaf(a0.x, w0, acc.x); acc.y = fmaf(a0.y, w0, acc.y);
    acc.z = fmaf(a1.x, w0, acc.z); acc.w = fmaf(a1.y, w0, acc.w);
    acc.x = fmaf(c0.x, w1, acc.x); acc.y = fmaf(c0.y, w1, acc.y);
    acc.z = fmaf(c1.x, w1, acc.z); acc.w = fmaf(c1.y, w1, acc.w);
    acc.x = fmaf(e0.x, w2, acc.x); acc.y = fmaf(e0.y, w2, acc.y);
    acc.z = fmaf(e1.x, w2, acc.z); acc.w = fmaf(e1.y, w2, acc.w);
    acc.x = fmaf(g0.x, w3, acc.x); acc.y = fmaf(g0.y, w3, acc.y);
    acc.z = fmaf(g1.x, w3, acc.z); acc.w = fmaf(g1.y, w3, acc.w);
  }
  for (; j + 4 < b1; j += 8) {
    int sa = srcs[j], sb = srcs[j + 4];
    float wa = dinv[sa] * di, wb = dinv[sb] * di;
    uint2 ra = *(const uint2*)(gh + (size_t)sa * DH + d4);
    uint2 rb = *(const uint2*)(gh + (size_t)sb * DH + d4);
    float2 a0 = unpack_half2(ra.x), a1 = unpack_half2(ra.y);
    float2 c0 = unpack_half2(rb.x), c1 = unpack_half2(rb.y);
    acc.x = fmaf(a0.x, wa, acc.x); acc.y = fmaf(a0.y, wa, acc.y);
    acc.z = fmaf(a1.x, wa, acc.z); acc.w = fmaf(a1.y, wa, acc.w);
    acc.x = fmaf(c0.x, wb, acc.x); acc.y = fmaf(c0.y, wb, acc.y);
    acc.z = fmaf(c1.x, wb, acc.z); acc.w = fmaf(c1.y, wb, acc.w);
  }
  if (j < b1) {
    int s = srcs[j];
    float w = dinv[s] * di;
    uint2 r = *(const uint2*)(gh + (size_t)s * DH + d4);
    float2 f0 = unpack_half2(r.x), f1 = unpack_half2(r.y);
    acc.x = fmaf(f0.x, w, acc.x); acc.y = fmaf(f0.y, w, acc.y);
    acc.z = fmaf(f1.x, w, acc.z); acc.w = fmaf(f1.y, w, acc.w);
  }
  acc.x += __shfl_xor(acc.x, 16, 64); acc.x += __shfl_xor(acc.x, 32, 64);
  acc.y += __shfl_xor(acc.y, 16, 64); acc.y += __shfl_xor(acc.y, 32, 64);
  acc.z += __shfl_xor(acc.z, 16, 64); acc.z += __shfl_xor(acc.z, 32, 64);
  acc.w += __shfl_xor(acc.w, 16, 64); acc.w += __shfl_xor(acc.w, 32, 64);
  if (lane < 16) {
    if (bias) {
      float4 bv = *(const float4*)&bias[d4];
      acc.x += bv.x; acc.y += bv.y; acc.z += bv.z; acc.w += bv.w;
    }
    if (relu) {
      acc.x = fmaxf(acc.x, 0.f); acc.y = fmaxf(acc.y, 0.f);
      acc.z = fmaxf(acc.z, 0.f); acc.w = fmaxf(acc.w, 0.f);
    }
    uint2 u;
    u.x = pack_half2(acc.x, acc.y);
    u.y = pack_half2(acc.z, acc.w);
    *(uint2*)&out[(size_t)gid * DH + d4] = u;
  }
}

// ---------------- G: row-per-lane-pair fused head, no barriers ---------------
// 64 thr = 1 wave; 32 rows/block; lane pair (h=0,1) owns cols h*32..h*32+31.
// Row state (ah -> z -> T) lives in per-row LDS lines, stride 68 (16B-aligned).
__global__ __launch_bounds__(64) void k_head_row(const __half* __restrict__ ah,
                                                 const float* __restrict__ W2,
                                                 const float* __restrict__ b2,
                                                 const float* __restrict__ Wp1,
                                                 const float* __restrict__ bp1,
                                                 const float* __restrict__ Wp2,
                                                 const float* __restrict__ bp2,
                                                 float* __restrict__ z,
                                                 float* __restrict__ p, int n) {
  __shared__ float buf0[HROWS][68];  // ah, then T
  __shared__ float buf1[HROWS][68];  // z
  int L = threadIdx.x;
  int m = L >> 1;
  int h = L & 1;
  int row = blockIdx.x * HROWS + m;
  bool valid = row < n;
  int c0 = h * 32;

  // stage ah half-row -> buf0 (fp32)
  {
    const __half* ar = ah + (size_t)row * 64 + c0;
#pragma unroll
    for (int q = 0; q < 8; ++q) {
      uint2 u = valid ? *(const uint2*)(ar + q * 4) : make_uint2(0u, 0u);
      float2 f0 = unpack_half2(u.x), f1 = unpack_half2(u.y);
      float4* d = (float4*)&buf0[m][c0 + q * 4];
      *d = make_float4(f0.x, f0.y, f1.x, f1.y);
    }
  }

  float acc[32];

  // ---- phase 1: z = ah@W2 + b2 ----
#pragma unroll
  for (int c = 0; c < 32; ++c) acc[c] = 0.f;
  for (int k = 0; k < 64; ++k) {
    float a = buf0[m][k];
    const float4* w = (const float4*)&W2[k * 64 + c0];
#pragma unroll
    for (int c4 = 0; c4 < 8; ++c4) {
      float4 wv = w[c4];
      acc[c4 * 4 + 0] = fmaf(a, wv.x, acc[c4 * 4 + 0]);
      acc[c4 * 4 + 1] = fmaf(a, wv.y, acc[c4 * 4 + 1]);
      acc[c4 * 4 + 2] = fmaf(a, wv.z, acc[c4 * 4 + 2]);
      acc[c4 * 4 + 3] = fmaf(a, wv.w, acc[c4 * 4 + 3]);
    }
  }
  {
    const float4* bv = (const float4*)&b2[c0];
    float* zr = valid ? &z[(size_t)row * 64 + c0] : nullptr;
#pragma unroll
    for (int c4 = 0; c4 < 8; ++c4) {
      float4 b = bv[c4];
      float4 o = make_float4(acc[c4 * 4 + 0] + b.x, acc[c4 * 4 + 1] + b.y,
                             acc[c4 * 4 + 2] + b.z, acc[c4 * 4 + 3] + b.w);
      *(float4*)&buf1[m][c0 + c4 * 4] = o;
      if (zr) *(float4*)&zr[c4 * 4] = o;
    }
  }

  // ---- phase 2: T = relu(z@Wp1 + bp1) ----
#pragma unroll
  for (int c = 0; c < 32; ++c) acc[c] = 0.f;
  for (int k = 0; k < 64; ++k) {
    float a = buf1[m][k];
    const float4* w = (const float4*)&Wp1[k * 64 + c0];
#pragma unroll
    for (int c4 = 0; c4 < 8; ++c4) {
      float4 wv = w[c4];
      acc[c4 * 4 + 0] = fmaf(a, wv.x, acc[c4 * 4 + 0]);
      acc[c4 * 4 + 1] = fmaf(a, wv.y, acc[c4 * 4 + 1]);
      acc[c4 * 4 + 2] = fmaf(a, wv.z, acc[c4 * 4 + 2]);
      acc[c4 * 4 + 3] = fmaf(a, wv.w, acc[c4 * 4 + 3]);
    }
  }
  {
    const float4* bv = (const float4*)&bp1[c0];
#pragma unroll
    for (int c4 = 0; c4 < 8; ++c4) {
      float4 b = bv[c4];
      float4 o;
      o.x = fmaxf(acc[c4 * 4 + 0] + b.x, 0.f);
      o.y = fmaxf(acc[c4 * 4 + 1] + b.y, 0.f);
      o.z = fmaxf(acc[c4 * 4 + 2] + b.z, 0.f);
      o.w = fmaxf(acc[c4 * 4 + 3] + b.w, 0.f);
      *(float4*)&buf0[m][c0 + c4 * 4] = o;  // ah dead; reuse for T
    }
  }

  // ---- phase 3: p = T@Wp2 + bp2 ----
#pragma unroll
  for (int c = 0; c < 32; ++c) acc[c] = 0.f;
  for (int k = 0; k < 64; ++k) {
    float a = buf0[m][k];
    const float4* w = (const float4*)&Wp2[k * 64 + c0];
#pragma unroll
    for (int c4 = 0; c4 < 8; ++c4) {
      float4 wv = w[c4];
      acc[c4 * 4 + 0] = fmaf(a, wv.x, acc[c4 * 4 + 0]);
      acc[c4 * 4 + 1] = fmaf(a, wv.y, acc[c4 * 4 + 1]);
      acc[c4 * 4 + 2] = fmaf(a, wv.z, acc[c4 * 4 + 2]);
      acc[c4 * 4 + 3] = fmaf(a, wv.w, acc[c4 * 4 + 3]);
    }
  }
  if (valid) {
    const float4* bv = (const float4*)&bp2[c0];
    float* pr = &p[(size_t)row * 64 + c0];
#pragma unroll
    for (int c4 = 0; c4 < 8; ++c4) {
      float4 b = bv[c4];
      float4 o = make_float4(acc[c4 * 4 + 0] + b.x, acc[c4 * 4 + 1] + b.y,
                             acc[c4 * 4 + 2] + b.z, acc[c4 * 4 + 3] + b.w);
      *(float4*)&pr[c4 * 4] = o;
    }
  }
}

extern "C" void kernel_launch(void* const* d_in, const int* in_sizes, int n_in,
                              void* d_out, int out_size, void* d_ws, size_t ws_size,
                              hipStream_t stream) {
  const float* x   = (const float*)d_in[0];
  const int*   ei  = (const int*)d_in[1];
  const float* W1  = (const float*)d_in[2];
  const float* b1  = (const float*)d_in[3];
  const float* W2  = (const float*)d_in[4];
  const float* b2  = (const float*)d_in[5];
  const float* Wp1 = (const float*)d_in[6];
  const float* bp1 = (const float*)d_in[7];
  const float* Wp2 = (const float*)d_in[8];
  const float* bp2 = (const float*)d_in[9];

  int n = in_sizes[0] / DIN;   // 50000
  int e = in_sizes[1] / 2;     // 800000
  const int* src = ei;
  const int* dst = ei + e;

  int nblkE = (e + ETILE - 1) / ETILE;            // 196
  int nbBins = (n + BIN_NODES - 1) / BIN_NODES;   // 391
  int gG = (n + 127) / 128;                       // 391
  int gH = (n + HROWS - 1) / HROWS;               // 1563

  // workspace layout (non-overlapping; ws is ~268MB)
  char* ws = (char*)d_ws;
  __half* gtab   = (__half*)ws;                            // [0, 6.4MB)   g1, later ah
  __half* htab   = (__half*)(ws + ((size_t)7 << 20));      // [7, 13.4MB)  h
  char*   ctrl   = ws + ((size_t)14 << 20);                // [14MB, ...)
  int*    binTot = (int*)(ctrl);                           // 512 i32
  int*    binOff = (int*)(ctrl + 4096);                    // 513 i32
  int*    binCur = (int*)(ctrl + 8192);                    // 512 i32
  int*    off    = (int*)(ctrl + 16384);                   // (n+1) i32 (~200KB)
  float*  dinv   = (float*)(ctrl + 16384 + (1 << 18));     // n f32
  int*    sp     = (int*)(ctrl + 16384 + (2 << 18));       // e i32 = 3.2MB
  int*    srcs   = sp + e;                                 // e i32 = 3.2MB (ends ~21MB)

  float* zout = (float*)d_out;
  float* pout = zout + (size_t)n * DH;

  // 0) zero bin totals (kernel, capture-safe)
  k_zero<<<1, 512, 0, stream>>>(binTot, NBINS);

  // A) gemm1 (x@W1 -> fp16 g1)  ||  bin histogram
  k_fusedA<<<gG + nblkE, 256, 0, stream>>>(x, W1, gtab, dst, binTot, n, e, gG);

  // B) scan bins
  k_binscan<<<1, 512, 0, stream>>>(binTot, binOff, binCur, e);

  // C) scatter edges into bin-grouped order
  k_scatter2<<<nblkE, 256, 0, stream>>>(src, dst, binCur, sp, e);

  // D) per-bin CSR: off, dinv, srcs
  k_bincsr<<<nbBins, 256, 0, stream>>>(sp, binOff, off, dinv, srcs, n, e);

  // E) h = relu(agg(g1) + b1) -> htab (fp16)
  k_agg<<<(n + 3) / 4, 256, 0, stream>>>(gtab, off, srcs, dinv, b1, htab, n, 1);

  // F) ah = agg(h) -> gtab (fp16; g1 dead)
  k_agg<<<(n + 3) / 4, 256, 0, stream>>>(htab, off, srcs, dinv, nullptr, gtab, n, 0);

  // G) z = ah@W2+b2 ; p = relu(z@Wp1+bp1)@Wp2+bp2  (row-per-lane-pair)
  k_head_row<<<gH, 64, 0, stream>>>(gtab, W2, b2, Wp1, bp1, Wp2, bp2, zout, pout, n);
}

// Round 11
// 141.806 us; speedup vs baseline: 1.8918x; 1.8918x over previous
//
#include <hip/hip_runtime.h>
#include <hip/hip_fp16.h>

#define DIN 128
#define DH 64
#define NBINS 512      // bin = dst >> 7 ; n=50000 -> bins 0..390 used
#define BIN_SHIFT 7
#define BIN_NODES 128
#define ETILE 4096     // edges per histogram/scatter block
#define EBUF 4096      // LDS edge buffer per bin (avg fill ~2046)

__device__ inline unsigned pack_half2(float a, float b) {
  __half2 h = __floats2half2_rn(a, b);
  return *(unsigned*)&h;
}
__device__ inline float2 unpack_half2(unsigned u) {
  __half2 h = *(__half2*)&u;
  return __half22float2(h);
}

// ---------------- zero helper (capture-safe) ----------------
__global__ __launch_bounds__(512) void k_zero(int* __restrict__ p, int n) {
  int i = blockIdx.x * blockDim.x + threadIdx.x;
  if (i < n) p[i] = 0;
}

// ---------------- A: fused  gemm1 (x@W1 -> fp16 g1)  ||  bin histogram ------
__global__ __launch_bounds__(256) void k_fusedA(const float* __restrict__ x,
                                                const float* __restrict__ W1,
                                                __half* __restrict__ g1,
                                                const int* __restrict__ dst,
                                                int* __restrict__ binTot,
                                                int n, int e, int gG) {
  __shared__ float xsT[32][132];
  __shared__ float ws[32 * 64];
  __shared__ int hh[NBINS];
  int t = threadIdx.x;
  int bid = blockIdx.x;

  if (bid >= gG) {  // ---- histogram part ----
    int b = bid - gG;
    for (int i = t; i < NBINS; i += 256) hh[i] = 0;
    __syncthreads();
    int lo = b * ETILE, hi = lo + ETILE; if (hi > e) hi = e;
    for (int i = lo + t; i < hi; i += 256) atomicAdd(&hh[dst[i] >> BIN_SHIFT], 1);
    __syncthreads();
    for (int i = t; i < NBINS; i += 256) if (hh[i]) atomicAdd(&binTot[i], hh[i]);
    return;
  }

  // ---- gemm part: [n,128]@[128,64] -> fp16 ----
  int row0 = bid * 128;
  int rg = t >> 4, cg = t & 15;
  int r0 = rg * 8, c0 = cg * 4;
  int lr = t >> 3, kq = t & 7;
  float4 acc[8];
#pragma unroll
  for (int i = 0; i < 8; ++i) acc[i] = make_float4(0.f, 0.f, 0.f, 0.f);

  for (int kc = 0; kc < DIN; kc += 32) {
#pragma unroll
    for (int it = 0; it < 4; ++it) {
      int r = it * 32 + lr;
      int gr = row0 + r;
      float4 v = make_float4(0.f, 0.f, 0.f, 0.f);
      if (gr < n) v = *(const float4*)&x[(size_t)gr * DIN + kc + kq * 4];
      xsT[kq * 4 + 0][r] = v.x;
      xsT[kq * 4 + 1][r] = v.y;
      xsT[kq * 4 + 2][r] = v.z;
      xsT[kq * 4 + 3][r] = v.w;
    }
#pragma unroll
    for (int j = 0; j < 8; ++j) ws[t + j * 256] = W1[(size_t)kc * 64 + t + j * 256];
    __syncthreads();
#pragma unroll
    for (int k = 0; k < 32; ++k) {
      float4 xa = *(const float4*)&xsT[k][r0];
      float4 xb = *(const float4*)&xsT[k][r0 + 4];
      float4 wv = *(const float4*)&ws[k * 64 + c0];
      float xr[8] = {xa.x, xa.y, xa.z, xa.w, xb.x, xb.y, xb.z, xb.w};
#pragma unroll
      for (int i = 0; i < 8; ++i) {
        acc[i].x = fmaf(xr[i], wv.x, acc[i].x);
        acc[i].y = fmaf(xr[i], wv.y, acc[i].y);
        acc[i].z = fmaf(xr[i], wv.z, acc[i].z);
        acc[i].w = fmaf(xr[i], wv.w, acc[i].w);
      }
    }
    __syncthreads();
  }
#pragma unroll
  for (int i = 0; i < 8; ++i) {
    int gr = row0 + r0 + i;
    if (gr < n) {
      uint2 u;
      u.x = pack_half2(acc[i].x, acc[i].y);
      u.y = pack_half2(acc[i].z, acc[i].w);
      *(uint2*)&g1[(size_t)gr * 64 + c0] = u;
    }
  }
}

// ---------------- B: scan 512 bin totals -> binOff, init binCur --------------
__global__ __launch_bounds__(512) void k_binscan(const int* __restrict__ binTot,
                                                 int* __restrict__ binOff,
                                                 int* __restrict__ binCur, int e) {
  __shared__ int sm[NBINS];
  int t = threadIdx.x;
  int v = binTot[t];
  sm[t] = v;
  __syncthreads();
  for (int ofs = 1; ofs < NBINS; ofs <<= 1) {
    int u = (t >= ofs) ? sm[t - ofs] : 0;
    __syncthreads();
    sm[t] += u;
    __syncthreads();
  }
  int ex = sm[t] - v;  // exclusive
  binOff[t] = ex;
  binCur[t] = ex;
  if (t == NBINS - 1) binOff[NBINS] = sm[NBINS - 1];
}

// ---------------- C: scatter into bin-grouped order (atomic cursors) ---------
__global__ __launch_bounds__(256) void k_scatter2(const int* __restrict__ src,
                                                  const int* __restrict__ dst,
                                                  int* __restrict__ binCur,
                                                  int* __restrict__ sp, int e) {
  __shared__ int hh[NBINS];
  __shared__ int base[NBINS];
  int t = threadIdx.x;
  for (int i = t; i < NBINS; i += 256) hh[i] = 0;
  __syncthreads();
  int lo = blockIdx.x * ETILE, hi = lo + ETILE; if (hi > e) hi = e;
  for (int i = lo + t; i < hi; i += 256) atomicAdd(&hh[dst[i] >> BIN_SHIFT], 1);
  __syncthreads();
  for (int i = t; i < NBINS; i += 256) {
    int c = hh[i];
    base[i] = c ? atomicAdd(&binCur[i], c) : 0;
  }
  __syncthreads();
  for (int i = t; i < NBINS; i += 256) hh[i] = 0;  // reuse as local cursors
  __syncthreads();
  for (int i = lo + t; i < hi; i += 256) {
    int d = dst[i];
    int bn = d >> BIN_SHIFT;
    int pos = base[bn] + atomicAdd(&hh[bn], 1);
    sp[pos] = (src[i] << BIN_SHIFT) | (d & (BIN_NODES - 1));
  }
}

// ---------------- D: per-bin deg + local scan -> off/dinv/srcs --------------
__global__ __launch_bounds__(256) void k_bincsr(const int* __restrict__ sp,
                                                const int* __restrict__ binOff,
                                                int* __restrict__ off,
                                                float* __restrict__ dinv,
                                                int* __restrict__ srcs,
                                                int n, int e) {
  __shared__ int dl[BIN_NODES];
  __shared__ int sc[BIN_NODES];
  __shared__ int curl[BIN_NODES];
  __shared__ int ebuf[EBUF];
  int b = blockIdx.x, t = threadIdx.x;
  if (t < BIN_NODES) dl[t] = 0;
  __syncthreads();
  int e0 = binOff[b];
  int e1 = binOff[b + 1];
  for (int i = e0 + t; i < e1; i += 256) {
    int u = sp[i];
    int k = i - e0;
    if (k < EBUF) ebuf[k] = u;
    atomicAdd(&dl[u & (BIN_NODES - 1)], 1);
  }
  __syncthreads();
  if (t < BIN_NODES) sc[t] = dl[t];
  __syncthreads();
  for (int ofs = 1; ofs < BIN_NODES; ofs <<= 1) {
    int v = (t < BIN_NODES && t >= ofs) ? sc[t - ofs] : 0;
    __syncthreads();
    if (t < BIN_NODES) sc[t] += v;
    __syncthreads();
  }
  int nbase = b * BIN_NODES;
  if (t < BIN_NODES) {
    int ex = e0 + sc[t] - dl[t];
    curl[t] = ex;
    int node = nbase + t;
    if (node < n) {
      off[node] = ex;
      dinv[node] = rsqrtf((float)(dl[t] + 1));
    }
  }
  if (b == 0 && t == 0) off[n] = e;
  __syncthreads();
  for (int i = e0 + t; i < e1; i += 256) {
    int k = i - e0;
    int u = (k < EBUF) ? ebuf[k] : sp[i];
    int l = u & (BIN_NODES - 1);
    int pos = atomicAdd(&curl[l], 1);
    srcs[pos] = u >> BIN_SHIFT;
  }
}

// ---------------- E/F: CSR gather-aggregate (fp16 in, fp16 out) -------------
__global__ __launch_bounds__(256) void k_agg(const __half* __restrict__ gh,
                                             const int* __restrict__ off,
                                             const int* __restrict__ srcs,
                                             const float* __restrict__ dinv,
                                             const float* __restrict__ bias,
                                             __half* __restrict__ out, int n, int relu) {
  int gid = blockIdx.x * 4 + (threadIdx.x >> 6);
  if (gid >= n) return;
  gid = __builtin_amdgcn_readfirstlane(gid);
  int lane = threadIdx.x & 63;
  int grp = lane >> 4;         // 0..3: edge slot
  int d4 = (lane & 15) * 4;    // feature quad
  float di = dinv[gid];
  float4 acc = make_float4(0.f, 0.f, 0.f, 0.f);
  if (grp == 0) {  // self-loop counted once
    uint2 raw = *(const uint2*)(gh + (size_t)gid * DH + d4);
    float2 f0 = unpack_half2(raw.x), f1 = unpack_half2(raw.y);
    float s = di * di;
    acc.x = f0.x * s; acc.y = f0.y * s; acc.z = f1.x * s; acc.w = f1.y * s;
  }
  int b0 = off[gid], b1 = off[gid + 1];
  int j = b0 + grp;
  for (; j + 12 < b1; j += 16) {  // 4 rows in flight per group
    int s0 = srcs[j], s1 = srcs[j + 4], s2 = srcs[j + 8], s3 = srcs[j + 12];
    float w0 = dinv[s0] * di, w1 = dinv[s1] * di;
    float w2 = dinv[s2] * di, w3 = dinv[s3] * di;
    uint2 r0 = *(const uint2*)(gh + (size_t)s0 * DH + d4);
    uint2 r1 = *(const uint2*)(gh + (size_t)s1 * DH + d4);
    uint2 r2 = *(const uint2*)(gh + (size_t)s2 * DH + d4);
    uint2 r3 = *(const uint2*)(gh + (size_t)s3 * DH + d4);
    float2 a0 = unpack_half2(r0.x), a1 = unpack_half2(r0.y);
    float2 c0 = unpack_half2(r1.x), c1 = unpack_half2(r1.y);
    float2 e0 = unpack_half2(r2.x), e1 = unpack_half2(r2.y);
    float2 g0 = unpack_half2(r3.x), g1 = unpack_half2(r3.y);
    acc.x = fmaf(a0.x, w0, acc.x); acc.y = fmaf(a0.y, w0, acc.y);
    acc.z = fmaf(a1.x, w0, acc.z); acc.w = fmaf(a1.y, w0, acc.w);
    acc.x = fmaf(c0.x, w1, acc.x); acc.y = fmaf(c0.y, w1, acc.y);
    acc.z = fmaf(c1.x, w1, acc.z); acc.w = fmaf(c1.y, w1, acc.w);
    acc.x = fmaf(e0.x, w2, acc.x); acc.y = fmaf(e0.y, w2, acc.y);
    acc.z = fmaf(e1.x, w2, acc.z); acc.w = fmaf(e1.y, w2, acc.w);
    acc.x = fmaf(g0.x, w3, acc.x); acc.y = fmaf(g0.y, w3, acc.y);
    acc.z = fmaf(g1.x, w3, acc.z); acc.w = fmaf(g1.y, w3, acc.w);
  }
  for (; j + 4 < b1; j += 8) {
    int sa = srcs[j], sb = srcs[j + 4];
    float wa = dinv[sa] * di, wb = dinv[sb] * di;
    uint2 ra = *(const uint2*)(gh + (size_t)sa * DH + d4);
    uint2 rb = *(const uint2*)(gh + (size_t)sb * DH + d4);
    float2 a0 = unpack_half2(ra.x), a1 = unpack_half2(ra.y);
    float2 c0 = unpack_half2(rb.x), c1 = unpack_half2(rb.y);
    acc.x = fmaf(a0.x, wa, acc.x); acc.y = fmaf(a0.y, wa, acc.y);
    acc.z = fmaf(a1.x, wa, acc.z); acc.w = fmaf(a1.y, wa, acc.w);
    acc.x = fmaf(c0.x, wb, acc.x); acc.y = fmaf(c0.y, wb, acc.y);
    acc.z = fmaf(c1.x, wb, acc.z); acc.w = fmaf(c1.y, wb, acc.w);
  }
  if (j < b1) {
    int s = srcs[j];
    float w = dinv[s] * di;
    uint2 r = *(const uint2*)(gh + (size_t)s * DH + d4);
    float2 f0 = unpack_half2(r.x), f1 = unpack_half2(r.y);
    acc.x = fmaf(f0.x, w, acc.x); acc.y = fmaf(f0.y, w, acc.y);
    acc.z = fmaf(f1.x, w, acc.z); acc.w = fmaf(f1.y, w, acc.w);
  }
  acc.x += __shfl_xor(acc.x, 16, 64); acc.x += __shfl_xor(acc.x, 32, 64);
  acc.y += __shfl_xor(acc.y, 16, 64); acc.y += __shfl_xor(acc.y, 32, 64);
  acc.z += __shfl_xor(acc.z, 16, 64); acc.z += __shfl_xor(acc.z, 32, 64);
  acc.w += __shfl_xor(acc.w, 16, 64); acc.w += __shfl_xor(acc.w, 32, 64);
  if (lane < 16) {
    if (bias) {
      float4 bv = *(const float4*)&bias[d4];
      acc.x += bv.x; acc.y += bv.y; acc.z += bv.z; acc.w += bv.w;
    }
    if (relu) {
      acc.x = fmaxf(acc.x, 0.f); acc.y = fmaxf(acc.y, 0.f);
      acc.z = fmaxf(acc.z, 0.f); acc.w = fmaxf(acc.w, 0.f);
    }
    uint2 u;
    u.x = pack_half2(acc.x, acc.y);
    u.y = pack_half2(acc.z, acc.w);
    *(uint2*)&out[(size_t)gid * DH + d4] = u;
  }
}

// ---------------- register-tiled GEMM: [n,64] @ [64,64] (+bias,+relu) --------
// 256 thr, tile 128 rows x 64 cols, per-thread 8 rows x 4 cols. Proven ~9us.
template <bool RELU, bool INHALF>
__global__ __launch_bounds__(256) void k_gemm_rt(const void* __restrict__ Av,
                                                 const float* __restrict__ W,
                                                 const float* __restrict__ bias,
                                                 float* __restrict__ out, int n) {
  constexpr int KC = 32;
  constexpr int MP = 132;  // 128 + 4 pad
  __shared__ float xsT[KC][MP];
  __shared__ float ws[KC * 64];
  __shared__ float bs[64];
  int t = threadIdx.x;
  if (t < 64) bs[t] = bias[t];
  int row0 = blockIdx.x * 128;
  int rg = t >> 4, cg = t & 15;
  int r0 = rg * 8, c0 = cg * 4;
  float4 acc[8];
#pragma unroll
  for (int i = 0; i < 8; ++i) acc[i] = make_float4(0.f, 0.f, 0.f, 0.f);

  int lr = t >> 3;  // staging row 0..31
  int kq = t & 7;   // staging k-quad

  for (int kc = 0; kc < DH; kc += KC) {
#pragma unroll
    for (int it = 0; it < 4; ++it) {
      int r = it * 32 + lr;
      int gr = row0 + r;
      float4 v = make_float4(0.f, 0.f, 0.f, 0.f);
      if (gr < n) {
        if (INHALF) {
          uint2 u = *(const uint2*)((const __half*)Av + (size_t)gr * DH + kc + kq * 4);
          float2 f0 = unpack_half2(u.x), f1 = unpack_half2(u.y);
          v = make_float4(f0.x, f0.y, f1.x, f1.y);
        } else {
          v = *(const float4*)&((const float*)Av)[(size_t)gr * DH + kc + kq * 4];
        }
      }
      xsT[kq * 4 + 0][r] = v.x;
      xsT[kq * 4 + 1][r] = v.y;
      xsT[kq * 4 + 2][r] = v.z;
      xsT[kq * 4 + 3][r] = v.w;
    }
#pragma unroll
    for (int j = 0; j < 8; ++j) {
      int idx = t + j * 256;
      ws[idx] = W[(size_t)kc * 64 + idx];
    }
    __syncthreads();
#pragma unroll
    for (int k = 0; k < KC; ++k) {
      float4 xa = *(const float4*)&xsT[k][r0];
      float4 xb = *(const float4*)&xsT[k][r0 + 4];
      float4 wv = *(const float4*)&ws[k * 64 + c0];
      float xr[8] = {xa.x, xa.y, xa.z, xa.w, xb.x, xb.y, xb.z, xb.w};
#pragma unroll
      for (int i = 0; i < 8; ++i) {
        acc[i].x = fmaf(xr[i], wv.x, acc[i].x);
        acc[i].y = fmaf(xr[i], wv.y, acc[i].y);
        acc[i].z = fmaf(xr[i], wv.z, acc[i].z);
        acc[i].w = fmaf(xr[i], wv.w, acc[i].w);
      }
    }
    __syncthreads();
  }

  float4 bv = *(const float4*)&bs[c0];
#pragma unroll
  for (int i = 0; i < 8; ++i) {
    int gr = row0 + r0 + i;
    if (gr < n) {
      float4 o = acc[i];
      o.x += bv.x; o.y += bv.y; o.z += bv.z; o.w += bv.w;
      if (RELU) {
        o.x = fmaxf(o.x, 0.f); o.y = fmaxf(o.y, 0.f);
        o.z = fmaxf(o.z, 0.f); o.w = fmaxf(o.w, 0.f);
      }
      *(float4*)&out[(size_t)gr * DH + c0] = o;
    }
  }
}

extern "C" void kernel_launch(void* const* d_in, const int* in_sizes, int n_in,
                              void* d_out, int out_size, void* d_ws, size_t ws_size,
                              hipStream_t stream) {
  const float* x   = (const float*)d_in[0];
  const int*   ei  = (const int*)d_in[1];
  const float* W1  = (const float*)d_in[2];
  const float* b1  = (const float*)d_in[3];
  const float* W2  = (const float*)d_in[4];
  const float* b2  = (const float*)d_in[5];
  const float* Wp1 = (const float*)d_in[6];
  const float* bp1 = (const float*)d_in[7];
  const float* Wp2 = (const float*)d_in[8];
  const float* bp2 = (const float*)d_in[9];

  int n = in_sizes[0] / DIN;   // 50000
  int e = in_sizes[1] / 2;     // 800000
  const int* src = ei;
  const int* dst = ei + e;

  int nblkE = (e + ETILE - 1) / ETILE;            // 196
  int nbBins = (n + BIN_NODES - 1) / BIN_NODES;   // 391
  int gG = (n + 127) / 128;                       // 391

  // workspace layout (non-overlapping; ws is ~268MB)
  char* ws = (char*)d_ws;
  __half* gtab   = (__half*)ws;                            // [0, 6.4MB)   g1, later ah
  __half* htab   = (__half*)(ws + ((size_t)7 << 20));      // [7, 13.4MB)  h
  char*   ctrl   = ws + ((size_t)14 << 20);                // [14MB, ...)
  int*    binTot = (int*)(ctrl);                           // 512 i32
  int*    binOff = (int*)(ctrl + 4096);                    // 513 i32
  int*    binCur = (int*)(ctrl + 8192);                    // 512 i32
  int*    off    = (int*)(ctrl + 16384);                   // (n+1) i32 (~200KB)
  float*  dinv   = (float*)(ctrl + 16384 + (1 << 18));     // n f32
  int*    sp     = (int*)(ctrl + 16384 + (2 << 18));       // e i32 = 3.2MB
  int*    srcs   = sp + e;                                 // e i32 = 3.2MB (ends ~21MB)
  float*  tbuf   = (float*)(ws + ((size_t)24 << 20));      // [24, 36.8MB) head T

  float* zout = (float*)d_out;
  float* pout = zout + (size_t)n * DH;

  // 0) zero bin totals (kernel, capture-safe)
  k_zero<<<1, 512, 0, stream>>>(binTot, NBINS);

  // A) gemm1 (x@W1 -> fp16 g1)  ||  bin histogram
  k_fusedA<<<gG + nblkE, 256, 0, stream>>>(x, W1, gtab, dst, binTot, n, e, gG);

  // B) scan bins
  k_binscan<<<1, 512, 0, stream>>>(binTot, binOff, binCur, e);

  // C) scatter edges into bin-grouped order
  k_scatter2<<<nblkE, 256, 0, stream>>>(src, dst, binCur, sp, e);

  // D) per-bin CSR: off, dinv, srcs
  k_bincsr<<<nbBins, 256, 0, stream>>>(sp, binOff, off, dinv, srcs, n, e);

  // E) h = relu(agg(g1) + b1) -> htab (fp16)
  k_agg<<<(n + 3) / 4, 256, 0, stream>>>(gtab, off, srcs, dinv, b1, htab, n, 1);

  // F) ah = agg(h) -> gtab (fp16; g1 dead)
  k_agg<<<(n + 3) / 4, 256, 0, stream>>>(htab, off, srcs, dinv, nullptr, gtab, n, 0);

  // G) head: z = ah@W2+b2 ; T = relu(z@Wp1+bp1) ; p = T@Wp2+bp2
  k_gemm_rt<false, true ><<<gG, 256, 0, stream>>>(gtab, W2, b2, zout, n);
  k_gemm_rt<true,  false><<<gG, 256, 0, stream>>>(zout, Wp1, bp1, tbuf, n);
  k_gemm_rt<false, false><<<gG, 256, 0, stream>>>(tbuf, Wp2, bp2, pout, n);
}